// Round 9
// baseline (1945.487 us; speedup 1.0000x reference)
//
#include <hip/hip_runtime.h>
#include <math.h>

// Problem constants (from reference)
#define TT 2048
#define BB 512
#define II 11
#define HH 33
#define NL 3
#define OO 18
#define SS 8                    // timesteps per epoch (barrier interval)
#define EPT (TT / SS)           // 256 working epochs per layer
#define NEP (EPT + NL - 1)      // 258 total epochs (pipeline fill/drain)
#define HROW 40                 // halves per LDS row (80 B; 34-half reads fit)

typedef _Float16 h2 __attribute__((ext_vector_type(2)));
typedef _Float16 h8 __attribute__((ext_vector_type(8)));   // 16 B -> ds_read_b128

// fast sigmoid / tanh via v_exp_f32 + v_rcp_f32 (saturate correctly at +-inf)
__device__ __forceinline__ float sigm_f(float x) {
    float e = __expf(-x);
    return __builtin_amdgcn_rcpf(1.0f + e);
}
__device__ __forceinline__ float tanh_f(float x) {
    float e = __expf(2.0f * x);
    return 1.0f - 2.0f * __builtin_amdgcn_rcpf(e + 1.0f);
}

// guarded fp32->fp16 row-slice loads (zero-pad past rem)
__device__ __forceinline__ h8 gldh8(const float* p, int k0, int rem) {
    h8 v;
    #pragma unroll
    for (int i = 0; i < 8; ++i) v[i] = (_Float16)((k0 + i < rem) ? p[k0 + i] : 0.0f);
    return v;
}
__device__ __forceinline__ h2 gldh2(const float* p, int k0, int rem) {
    h2 v;
    v.x = (_Float16)((k0 + 0 < rem) ? p[k0 + 0] : 0.0f);
    v.y = (_Float16)((k0 + 1 < rem) ? p[k0 + 1] : 0.0f);
    return v;
}

__device__ __forceinline__ h2 u2h(unsigned u) { return __builtin_bit_cast(h2, u); }

// v_dot2_f32_f16: 2 MACs/op, fp32 accumulate
#define FD(a, p, q) a = __builtin_amdgcn_fdot2((p), (q), a, false)
// one h8 input slice against all 4 gate rows: 4 chains, 8cy dep spacing
#define DQ4(v, w0, w1, w2, w3) do { \
    FD(a0,(v).s01,(w0).s01); FD(a1,(v).s01,(w1).s01); FD(a2,(v).s01,(w2).s01); FD(a3,(v).s01,(w3).s01); \
    FD(a0,(v).s23,(w0).s23); FD(a1,(v).s23,(w1).s23); FD(a2,(v).s23,(w2).s23); FD(a3,(v).s23,(w3).s23); \
    FD(a0,(v).s45,(w0).s45); FD(a1,(v).s45,(w1).s45); FD(a2,(v).s45,(w2).s45); FD(a3,(v).s45,(w3).s45); \
    FD(a0,(v).s67,(w0).s67); FD(a1,(v).s67,(w1).s67); FD(a2,(v).s67,(w2).s67); FD(a3,(v).s67,(w3).s67); \
} while (0)

// READLANE-RECURRENCE epoch LSTM. All-round model (R0-R8): step time =
// (insts x 2cy x waves/SIMD) + ~800cy of serial in-order fabric (per-step
// barrier + drain + LDS round trips + tail). Independent work does NOT fill
// the fabric (R8) -- it must be REMOVED from the per-step path:
//   * own-h recurrence stays entirely IN-WAVE and LDS-FREE: after the tail,
//     v_readlane pulls each unit's fp16 h into SGPRs (exec-independent),
//     scalar packs build 17 packed-fp16 pairs (SALU -- free pipe), and the
//     next step's own-side v_dot2_f32_f16 sources them directly as the one
//     legal SGPR operand. No ds_write->ds_read round trip (R7's mistake),
//     no per-step barrier (champion's cost).
//   * inter-layer handoff batched in epochs of 8 steps (R7's proven-correct
//     skeleton: parity ping-pong, 258 barriers total instead of 2050).
//   * wave2 spare lanes (33..54) prefetch next epoch's x; vmcnt drains once
//     per epoch at the barrier, off the step path.
// grid = 512 blocks (one batch element), block = 192 threads (3 waves, one
// layer each; lanes 0..32 = units, weights zero elsewhere -> garbage lanes
// compute h=0, never read).
__global__ __launch_bounds__(192, 1) void lstm_rl_kernel(
    const float* __restrict__ x,
    const float* __restrict__ Wih0, const float* __restrict__ Whh0,
    const float* __restrict__ bih0, const float* __restrict__ bhh0,
    const float* __restrict__ Wih1, const float* __restrict__ Whh1,
    const float* __restrict__ bih1, const float* __restrict__ bhh1,
    const float* __restrict__ Wih2, const float* __restrict__ Whh2,
    const float* __restrict__ bih2, const float* __restrict__ bhh2,
    const float* __restrict__ W1, const float* __restrict__ b1,
    const float* __restrict__ W2, const float* __restrict__ b2,
    float* __restrict__ hidden_out,   // [3, 512, 33]
    float* __restrict__ outp)         // [3, 512, 18]
{
    __shared__ __align__(16) _Float16 xbuf[2][SS][HROW];      // x epoch ping-pong
    __shared__ __align__(16) _Float16 hbuf[2][2][SS][HROW];   // [par][edge l->l+1]
    __shared__ float hfin[NL][HH + 1];
    __shared__ float h1s[NL][4 * OO];

    const int tid  = threadIdx.x;
    const int bg   = blockIdx.x;
    const int lane = tid & 63;
    const int wid  = tid >> 6;          // layer of this wave (0..2)
    const int j    = lane;              // unit within layer
    const bool cl  = (lane < HH);       // compute lane

    // ---- zero LDS comm buffers (pads stay zero forever) ----
    for (int f = tid; f < 2 * SS * HROW; f += 192) ((_Float16*)xbuf)[f] = (_Float16)0.0f;
    for (int f = tid; f < 2 * 2 * SS * HROW; f += 192) ((_Float16*)hbuf)[f] = (_Float16)0.0f;

    // ---- per-lane weights ----
    // input side: 4 gates x (4 h8 + 1 h2) = 34 halves (x for l0, prev-h else)
    // own side:   4 gates x 17 h2 packed pairs (k 0..33, 33 zero)
    h8 z8 = {0,0,0,0,0,0,0,0};
    h2 z2 = {(_Float16)0.0f, (_Float16)0.0f};
    h8 wi[4][4]; h2 wit[4]; h2 wh[4][17];
    #pragma unroll
    for (int g = 0; g < 4; ++g) {
        #pragma unroll
        for (int q = 0; q < 4; ++q) wi[g][q] = z8;
        wit[g] = z2;
        #pragma unroll
        for (int r = 0; r < 17; ++r) wh[g][r] = z2;
    }
    float b0 = 0.0f, b1v = 0.0f, b2v = 0.0f, b3v = 0.0f;

    if (cl) {
        const int l = wid;
        const float* bip = (l == 0) ? bih0 : (l == 1) ? bih1 : bih2;
        const float* bhp = (l == 0) ? bhh0 : (l == 1) ? bhh1 : bhh2;
        b0  = bip[0 * HH + j] + bhp[0 * HH + j];
        b1v = bip[1 * HH + j] + bhp[1 * HH + j];
        b2v = bip[2 * HH + j] + bhp[2 * HH + j];
        b3v = bip[3 * HH + j] + bhp[3 * HH + j];

        const float* Wi = (l == 0) ? Wih0 : (l == 1) ? Wih1 : Wih2;
        const float* Wh = (l == 0) ? Whh0 : (l == 1) ? Whh1 : Whh2;
        const int kin = (l == 0) ? II : HH;
        #pragma unroll
        for (int g = 0; g < 4; ++g) {
            const float* rw = Wi + (g * HH + j) * kin;
            wi[g][0] = gldh8(rw, 0,  kin); wi[g][1] = gldh8(rw, 8,  kin);
            wi[g][2] = gldh8(rw, 16, kin); wi[g][3] = gldh8(rw, 24, kin);
            wit[g]   = gldh2(rw, 32, kin);
            const float* rh = Wh + (g * HH + j) * HH;
            #pragma unroll
            for (int r = 0; r < 17; ++r) wh[g][r] = gldh2(rh, 2 * r, HH);
        }
    }

    // ---- x prefetch lanes: wave2 lanes 33..54, 22 coalesced float4 / epoch ----
    const int  pl   = lane - HH;                  // 0..21 valid
    const bool pfl  = (wid == 2) && (pl >= 0) && (pl < 22);
    const float* xblk = x + (size_t)bg * TT * II;

    __syncthreads();                              // zero-init complete
    if (pfl) {                                    // stage epoch-0 x (t = 0..7)
        const float4 v = *(const float4*)(xblk + 4 * pl);
        #pragma unroll
        for (int q = 0; q < 4; ++q) {
            const int f = 4 * pl + q;             // 0..87
            const int t = (f * 373) >> 12;        // f / 11 (exact for f < 88)
            const int i = f - 11 * t;
            xbuf[0][t][i] = (_Float16)((&v.x)[q]);
        }
    }
    __syncthreads();

    // ---- steady state ----
    float c = 0.0f;
    unsigned shp[17];                             // packed fp16 h pairs (SGPR)
    #pragma unroll
    for (int r = 0; r < 17; ++r) shp[r] = 0u;

    const _Float16* inb2[2];
    if (wid == 0) { inb2[0] = &xbuf[0][0][0];            inb2[1] = &xbuf[1][0][0]; }
    else          { inb2[0] = &hbuf[0][wid - 1][0][0];   inb2[1] = &hbuf[1][wid - 1][0][0]; }
    const int oe = (wid < 2) ? wid : 0;
    _Float16* ob2[2] = { &hbuf[1][oe][0][0], &hbuf[0][oe][0][0] };   // write par^1
    const bool haveout = (wid < 2);

    for (int e = 0; e < NEP; ++e) {
        const int par = e & 1;

        // A) issue x prefetch for epoch e+1 (latency hidden under 8 steps)
        float4 pv;
        const bool pf = pfl && (e < EPT - 1);
        if (pf) pv = *(const float4*)(xblk + (size_t)(e + 1) * (SS * II) + 4 * pl);

        // B) compute epoch (wave-uniform activity)
        const bool act = (e >= wid) && (e - wid < EPT);
        if (act) {
            const _Float16* inb  = inb2[par];
            _Float16*       ob   = ob2[par];
            const bool      last = (e == EPT - 1 + wid);

            #pragma unroll
            for (int k = 0; k < SS; ++k) {
                // input vector for this step (stable epoch buffer; 5 ds_reads,
                // latency hides under the own-side dots below)
                const _Float16* ri = inb + k * HROW;
                const h8 vi0 = ((const h8*)ri)[0], vi1 = ((const h8*)ri)[1];
                const h8 vi2 = ((const h8*)ri)[2], vi3 = ((const h8*)ri)[3];
                const h2 vit = *(const h2*)(ri + 32);

                float a0 = b0, a1 = b1v, a2 = b2v, a3 = b3v;
                // ---- own-side: 68 fdot2 sourcing packed-h SGPR pairs ----
                #pragma unroll
                for (int r = 0; r < 17; ++r) {
                    const h2 sv = u2h(shp[r]);
                    FD(a0, wh[0][r], sv); FD(a1, wh[1][r], sv);
                    FD(a2, wh[2][r], sv); FD(a3, wh[3][r], sv);
                }
                // ---- input-side: 68 fdot2 from LDS-loaded vector ----
                DQ4(vi0, wi[0][0], wi[1][0], wi[2][0], wi[3][0]);
                DQ4(vi1, wi[0][1], wi[1][1], wi[2][1], wi[3][1]);
                DQ4(vi2, wi[0][2], wi[1][2], wi[2][2], wi[3][2]);
                DQ4(vi3, wi[0][3], wi[1][3], wi[2][3], wi[3][3]);
                FD(a0, vit, wit[0]); FD(a1, vit, wit[1]);
                FD(a2, vit, wit[2]); FD(a3, vit, wit[3]);

                // ---- tail ----
                const float ig = sigm_f(a0);
                const float fg = sigm_f(a1);
                const float gg = tanh_f(a2);
                const float og = sigm_f(a3);
                c = __builtin_fmaf(fg, c, ig * gg);
                const float hnew = og * tanh_f(c);

                // ---- broadcast: h -> fp16 -> SGPR packed pairs (no LDS) ----
                const _Float16 h16 = (_Float16)hnew;
                const unsigned hu = (unsigned)__builtin_bit_cast(unsigned short, h16);
                #pragma unroll
                for (int r = 0; r < 16; ++r) {
                    const unsigned lo = (unsigned)__builtin_amdgcn_readlane((int)hu, 2 * r);
                    const unsigned hi = (unsigned)__builtin_amdgcn_readlane((int)hu, 2 * r + 1);
                    shp[r] = (lo & 0xffffu) | (hi << 16);    // s_pack (SALU)
                }
                shp[16] = ((unsigned)__builtin_amdgcn_readlane((int)hu, 32)) & 0xffffu;

                // ---- handoff to layer l+1 (read next epoch; barrier-ordered) ----
                if (cl && haveout) ob[k * HROW + j] = h16;
                if (k == SS - 1 && last && cl) {
                    hidden_out[((size_t)wid * BB + bg) * HH + j] = hnew;
                    hfin[wid][j] = hnew;
                }
            }
        }

        // C) land prefetched x (vmcnt drains here, once per epoch)
        if (pf) {
            _Float16* xw = &xbuf[par ^ 1][0][0];
            #pragma unroll
            for (int q = 0; q < 4; ++q) {
                const int f = 4 * pl + q;
                const int t = (f * 373) >> 12;
                const int i = f - 11 * t;
                xw[t * HROW + i] = (_Float16)((&pv.x)[q]);
            }
        }
        __syncthreads();
    }

    // ---- fused MLP head (hfin complete after the final barrier) ----
    if (tid < 4 * OO) {                   // 72 threads x 3 layers
        #pragma unroll
        for (int ml = 0; ml < NL; ++ml) {
            float a = b1[tid];
            #pragma unroll
            for (int k = 0; k < HH; ++k) a += hfin[ml][k] * W1[tid * HH + k];
            h1s[ml][tid] = 0.5f * a * (1.0f + erff(a * 0.70710678118654752f));
        }
    }
    __syncthreads();
    if (tid < NL * OO) {                  // 54 threads
        const int ol = tid / OO, o = tid % OO;
        float a = b2[o];
        #pragma unroll
        for (int m = 0; m < 4 * OO; ++m) a += h1s[ol][m] * W2[o * (4 * OO) + m];
        outp[((size_t)ol * BB + bg) * OO + o] = a;
    }
}

extern "C" void kernel_launch(void* const* d_in, const int* in_sizes, int n_in,
                              void* d_out, int out_size, void* d_ws, size_t ws_size,
                              hipStream_t stream) {
    const float* x    = (const float*)d_in[0];
    const float* Wih0 = (const float*)d_in[1];
    const float* Whh0 = (const float*)d_in[2];
    const float* bih0 = (const float*)d_in[3];
    const float* bhh0 = (const float*)d_in[4];
    const float* Wih1 = (const float*)d_in[5];
    const float* Whh1 = (const float*)d_in[6];
    const float* bih1 = (const float*)d_in[7];
    const float* bhh1 = (const float*)d_in[8];
    const float* Wih2 = (const float*)d_in[9];
    const float* Whh2 = (const float*)d_in[10];
    const float* bih2 = (const float*)d_in[11];
    const float* bhh2 = (const float*)d_in[12];
    const float* W1   = (const float*)d_in[13];
    const float* b1   = (const float*)d_in[14];
    const float* W2   = (const float*)d_in[15];
    const float* b2   = (const float*)d_in[16];

    float* out    = (float*)d_out;                 // [3,512,18] = 27648 floats
    float* hidden = out + NL * BB * OO;            // [3,512,33] = 50688 floats

    lstm_rl_kernel<<<BB, 192, 0, stream>>>(
        x, Wih0, Whh0, bih0, bhh0, Wih1, Whh1, bih1, bhh1,
        Wih2, Whh2, bih2, bhh2, W1, b1, W2, b2, hidden, out);
}

// Round 10
// 1086.934 us; speedup vs baseline: 1.7899x; 1.7899x over previous
//
#include <hip/hip_runtime.h>
#include <math.h>

// Problem constants (from reference)
#define TT 2048
#define BB 512
#define II 11
#define HH 33
#define NL 3
#define OO 18
#define HSLOT 48          // halves per LDS vector slot (96 B, 16B-aligned slots)
#define XPAD 16           // halves per staged-x row (32 B, b128-aligned reads)
#define XROWS (TT + 8)    // overhang reads at s+1..s+3 stay in-bounds

typedef _Float16 h2 __attribute__((ext_vector_type(2)));
typedef _Float16 h8 __attribute__((ext_vector_type(8)));   // 16 B -> ds_read_b128

// fast sigmoid / tanh via v_exp_f32 + v_rcp_f32 (saturate correctly at +-inf)
__device__ __forceinline__ float sigm_f(float x) {
    float e = __expf(-x);
    return __builtin_amdgcn_rcpf(1.0f + e);
}
__device__ __forceinline__ float tanh_f(float x) {
    float e = __expf(2.0f * x);
    return 1.0f - 2.0f * __builtin_amdgcn_rcpf(e + 1.0f);
}

// guarded fp32->fp16 row-slice loads (zero-pad past rem)
__device__ __forceinline__ h8 gldh8(const float* p, int k0, int rem) {
    h8 v;
    #pragma unroll
    for (int i = 0; i < 8; ++i) v[i] = (_Float16)((k0 + i < rem) ? p[k0 + i] : 0.0f);
    return v;
}
__device__ __forceinline__ h2 gldh2(const float* p, int k0, int rem) {
    h2 v;
    v.x = (_Float16)((k0 + 0 < rem) ? p[k0 + 0] : 0.0f);
    v.y = (_Float16)((k0 + 1 < rem) ? p[k0 + 1] : 0.0f);
    return v;
}

// v_dot2_f32_f16: 2 MACs/op, fp32 accumulate
#define FD(a, p, q) a = __builtin_amdgcn_fdot2((p), (q), a, false)
// one h8 slice against 4 gate rows into 4 named accumulator chains
#define DQ4X(A0, A1, A2, A3, v, w0, w1, w2, w3) do { \
    FD(A0,(v).s01,(w0).s01); FD(A1,(v).s01,(w1).s01); FD(A2,(v).s01,(w2).s01); FD(A3,(v).s01,(w3).s01); \
    FD(A0,(v).s23,(w0).s23); FD(A1,(v).s23,(w1).s23); FD(A2,(v).s23,(w2).s23); FD(A3,(v).s23,(w3).s23); \
    FD(A0,(v).s45,(w0).s45); FD(A1,(v).s45,(w1).s45); FD(A2,(v).s45,(w2).s45); FD(A3,(v).s45,(w3).s45); \
    FD(A0,(v).s67,(w0).s67); FD(A1,(v).s67,(w1).s67); FD(A2,(v).s67,(w2).s67); FD(A3,(v).s67,(w3).s67); \
} while (0)

// SKEW-2 DECOUPLED-INPUT LSTM (champion R6 + one structural change).
// All-round fit: v_dot2_f32_f16 is ~4cy/wave (half-rate) -> the champion's
// 136-dot block (544cy) was the dominant critical-path item. With inter-layer
// skew 2 (layer l computes t = s - 2l; SAME math, longer pipeline), the
// input-side vector h_{l-1} for step s+1 is finalized at step s-1 -> its 68
// dots move OFF the critical path: computed during step s, overlapping the
// tail's transcendental latency. Per-step chain: vo-read(140) + own-dots
// 68x4cy(272) + tail(170) + write/barrier(150) ~= 830cy vs champion ~1220.
// Skew-2 needs a 3-ring h buffer: at step s (ring r=s%3), writes go to
// ring[r]; vo (own h(s-1)) and vi-prefetch both read ring[(r+2)%3]; layer
// l+1 consumes the slot written 2 steps ago -- race-free at every step.
// Everything else is the measured-1042us R6 champion: 128 thr (2 waves,
// 1 wave/SIMD), x fully staged in LDS, zero global ops in loop, same dot
// macros, same tail numerics, one barrier per superstep.
__global__ __launch_bounds__(128, 1) void lstm_skew2_kernel(
    const float* __restrict__ x,
    const float* __restrict__ Wih0, const float* __restrict__ Whh0,
    const float* __restrict__ bih0, const float* __restrict__ bhh0,
    const float* __restrict__ Wih1, const float* __restrict__ Whh1,
    const float* __restrict__ bih1, const float* __restrict__ bhh1,
    const float* __restrict__ Wih2, const float* __restrict__ Whh2,
    const float* __restrict__ bih2, const float* __restrict__ bhh2,
    const float* __restrict__ W1, const float* __restrict__ b1,
    const float* __restrict__ W2, const float* __restrict__ b2,
    float* __restrict__ hidden_out,   // [3, 512, 33]
    float* __restrict__ outp)         // [3, 512, 18]
{
    __shared__ __align__(16) _Float16 xst[XROWS][XPAD];       // staged x, 64.3 KB
    __shared__ __align__(16) _Float16 buf[3][NL + 1][HSLOT];  // 3-ring h/x slots
    __shared__ float hfin[NL][HH + 1];
    __shared__ float h1s[NL][4 * OO];

    const int tid = threadIdx.x;
    const int bg  = blockIdx.x;

    for (int i = tid; i < 3 * (NL + 1) * HSLOT; i += 128)
        ((_Float16*)buf)[i] = (_Float16)0.0f;

    // ---- x staging (R6 scheme): pad cells zeroed; real cells filled ----
    for (int f = tid; f < XROWS * XPAD; f += 128) {
        const int i = f & (XPAD - 1);
        const int t = f >> 4;
        if (i >= II || t >= TT) ((_Float16*)xst)[f] = (_Float16)0.0f;
    }
    {
        const float* xblk = x + (size_t)bg * TT * II;
        const float4* xf4 = (const float4*)xblk;          // 22528 floats = 5632 f4
        for (int f4 = tid; f4 < (TT * II) / 4; f4 += 128) {
            const float4 v = xf4[f4];
            const int e0 = 4 * f4;
            #pragma unroll
            for (int e = 0; e < 4; ++e) {
                const int idx = e0 + e;
                const int t = idx / II;                   // magic-mul
                const int i = idx - t * II;
                xst[t][i] = (_Float16)((&v.x)[e]);
            }
        }
    }

    const bool comp = (tid < 99);
    const int  u    = tid;
    const int  l    = (u < 33) ? 0 : (u < 66) ? 1 : 2;
    const int  j    = u - 33 * l;

    // ---- per-lane weights: 4 gates x (input 34 + own 34) halves (R4 form) ----
    h8 z8 = {0,0,0,0,0,0,0,0};
    h2 z2 = {(_Float16)0.0f, (_Float16)0.0f};
    h8 x00=z8,x01=z8,x02=z8,x03=z8; h2 x0t=z2;   // gate i, input side (W_ih row)
    h8 x10=z8,x11=z8,x12=z8,x13=z8; h2 x1t=z2;   // gate f
    h8 x20=z8,x21=z8,x22=z8,x23=z8; h2 x2t=z2;   // gate g
    h8 x30=z8,x31=z8,x32=z8,x33=z8; h2 x3t=z2;   // gate o
    h8 h00=z8,h01=z8,h02=z8,h03=z8; h2 h0t=z2;   // gate i, own-h side (W_hh row)
    h8 h10=z8,h11=z8,h12=z8,h13=z8; h2 h1t=z2;
    h8 h20=z8,h21=z8,h22=z8,h23=z8; h2 h2t=z2;
    h8 h30=z8,h31=z8,h32=z8,h33=z8; h2 h3t=z2;
    float b0 = 0.0f, b1v = 0.0f, b2v = 0.0f, b3v = 0.0f;

    if (comp) {
        const float* bip = (l == 0) ? bih0 : (l == 1) ? bih1 : bih2;
        const float* bhp = (l == 0) ? bhh0 : (l == 1) ? bhh1 : bhh2;
        b0  = bip[0 * HH + j] + bhp[0 * HH + j];
        b1v = bip[1 * HH + j] + bhp[1 * HH + j];
        b2v = bip[2 * HH + j] + bhp[2 * HH + j];
        b3v = bip[3 * HH + j] + bhp[3 * HH + j];

        const float* Wi = (l == 0) ? Wih0 : (l == 1) ? Wih1 : Wih2;
        const float* Wh = (l == 0) ? Whh0 : (l == 1) ? Whh1 : Whh2;
        const int kin = (l == 0) ? II : HH;
        const float* r0 = Wi + (0 * HH + j) * kin;
        const float* r1 = Wi + (1 * HH + j) * kin;
        const float* r2 = Wi + (2 * HH + j) * kin;
        const float* r3 = Wi + (3 * HH + j) * kin;
        x00=gldh8(r0,0,kin); x01=gldh8(r0,8,kin); x02=gldh8(r0,16,kin); x03=gldh8(r0,24,kin); x0t=gldh2(r0,32,kin);
        x10=gldh8(r1,0,kin); x11=gldh8(r1,8,kin); x12=gldh8(r1,16,kin); x13=gldh8(r1,24,kin); x1t=gldh2(r1,32,kin);
        x20=gldh8(r2,0,kin); x21=gldh8(r2,8,kin); x22=gldh8(r2,16,kin); x23=gldh8(r2,24,kin); x2t=gldh2(r2,32,kin);
        x30=gldh8(r3,0,kin); x31=gldh8(r3,8,kin); x32=gldh8(r3,16,kin); x33=gldh8(r3,24,kin); x3t=gldh2(r3,32,kin);
        const float* s0 = Wh + (0 * HH + j) * HH;
        const float* s1 = Wh + (1 * HH + j) * HH;
        const float* s2 = Wh + (2 * HH + j) * HH;
        const float* s3 = Wh + (3 * HH + j) * HH;
        h00=gldh8(s0,0,HH); h01=gldh8(s0,8,HH); h02=gldh8(s0,16,HH); h03=gldh8(s0,24,HH); h0t=gldh2(s0,32,HH);
        h10=gldh8(s1,0,HH); h11=gldh8(s1,8,HH); h12=gldh8(s1,16,HH); h13=gldh8(s1,24,HH); h1t=gldh2(s1,32,HH);
        h20=gldh8(s2,0,HH); h21=gldh8(s2,8,HH); h22=gldh8(s2,16,HH); h23=gldh8(s2,24,HH); h2t=gldh2(s2,32,HH);
        h30=gldh8(s3,0,HH); h31=gldh8(s3,8,HH); h32=gldh8(s3,16,HH); h33=gldh8(s3,24,HH); h3t=gldh2(s3,32,HH);
    }

    __syncthreads();   // staging + ring zero-init complete

    float c = 0.0f;
    // carried input-side partial sums (bias folded in); valid for the NEXT step
    float p0 = b0, p1 = b1v, p2 = b2v, p3 = b3v;

    // ring pointers (compile-time ring index at every call site)
    const _Float16* vip[3] = { &buf[0][l][0],     &buf[1][l][0],     &buf[2][l][0] };
    const _Float16* vop[3] = { &buf[0][l+1][0],   &buf[1][l+1][0],   &buf[2][l+1][0] };
    _Float16*       wr3[3] = { &buf[0][l+1][j],   &buf[1][l+1][j],   &buf[2][l+1][j] };
    const _Float16* xst0   = &xst[0][0];

    // input-side dot block: reads the vector at rn, refreshes p0..p3
    auto prefetch_in = [&](const _Float16* rn) __attribute__((always_inline)) {
        const h8* VI = (const h8*)rn;
        const h8 vi0 = VI[0], vi1 = VI[1], vi2 = VI[2], vi3 = VI[3];
        const h2 vit = *(const h2*)(rn + 32);
        float n0 = b0, n1 = b1v, n2 = b2v, n3 = b3v;
        DQ4X(n0, n1, n2, n3, vi0, x00, x10, x20, x30);
        DQ4X(n0, n1, n2, n3, vi1, x01, x11, x21, x31);
        DQ4X(n0, n1, n2, n3, vi2, x02, x12, x22, x32);
        DQ4X(n0, n1, n2, n3, vi3, x03, x13, x23, x33);
        FD(n0, vit, x0t); FD(n1, vit, x1t);
        FD(n2, vit, x2t); FD(n3, vit, x3t);
        p0 = n0; p1 = n1; p2 = n2; p3 = n3;
    };

    // pre-loop: input partials for step 0 (l0: xst row 0; l>0: ring2 zeros,
    // overwritten before first use at their first nactive step)
    if (comp) prefetch_in((l == 0) ? xst0 : vip[2]);
    __syncthreads();

    // own-side + tail + write for step s at ring r; then prefetch for s+1
    auto core = [&](int s, int r, bool out) __attribute__((always_inline)) {
        // own-h vector h_l(s-1): ring (r+2)%3, slot l+1 (written last step)
        const _Float16* ro = vop[(r + 2) % 3];
        const h8* VO = (const h8*)ro;
        const h8 vo0 = VO[0], vo1 = VO[1], vo2 = VO[2], vo3 = VO[3];
        const h2 vot = *(const h2*)(ro + 32);

        // 68 own-side fdot2 as 8 chains (4 gates x lo/hi halves)
        float o0a=0.f,o1a=0.f,o2a=0.f,o3a=0.f;
        float o0b=0.f,o1b=0.f,o2b=0.f,o3b=0.f;
        DQ4X(o0a, o1a, o2a, o3a, vo0, h00, h10, h20, h30);
        DQ4X(o0a, o1a, o2a, o3a, vo1, h01, h11, h21, h31);
        DQ4X(o0b, o1b, o2b, o3b, vo2, h02, h12, h22, h32);
        DQ4X(o0b, o1b, o2b, o3b, vo3, h03, h13, h23, h33);
        FD(o0b, vot, h0t); FD(o1b, vot, h1t);
        FD(o2b, vot, h2t); FD(o3b, vot, h3t);

        const float s0 = p0 + (o0a + o0b);   // gate i (p includes bias)
        const float s1 = p1 + (o1a + o1b);   // gate f
        const float s2 = p2 + (o2a + o2b);   // gate g
        const float s3 = p3 + (o3a + o3b);   // gate o

        // tail (identical numerics to champion)
        const float ig = sigm_f(s0);
        const float fg = sigm_f(s1);
        const float gg = tanh_f(s2);
        const float og = sigm_f(s3);
        c = __builtin_fmaf(fg, c, ig * gg);
        const float hnew = og * tanh_f(c);

        *wr3[r] = (_Float16)hnew;            // slot l+1, ring r
        if (out && (s - 2 * l == TT - 1)) {
            hidden_out[((size_t)l * BB + bg) * HH + j] = hnew;
            hfin[l][j] = hnew;
        }
    };

    // one superstep; r/check/out are compile-time at call sites
    auto step = [&](int s, int r, bool check, bool out)
        __attribute__((always_inline)) {
        if (!check) {
            if (comp) {
                core(s, r, false);
                // input-side dots for s+1: l0 from xst[s+1]; l>0 from the
                // h_{l-1} slot finalized at step s-1 (ring (r+2)%3, slot l).
                // Independent of the tail -> overlaps its latency.
                prefetch_in((l == 0) ? (xst0 + ((s + 1) << 4)) : vip[(r + 2) % 3]);
            }
        } else {
            const bool act  = comp && (s >= 2 * l) && (s - 2 * l < TT);
            const bool nact = comp && (s + 1 >= 2 * l) && (s + 1 - 2 * l < TT);
            if (act)  core(s, r, out);
            if (nact) prefetch_in((l == 0) ? (xst0 + ((s + 1) << 4)) : vip[(r + 2) % 3]);
        }
        __syncthreads();
    };

    // prologue (pipeline fill, masked): s = 0..5
    step(0, 0, true, false);
    step(1, 1, true, false);
    step(2, 2, true, false);
    step(3, 0, true, false);
    step(4, 1, true, false);
    step(5, 2, true, false);
    // steady state: s = 6..2045 (all layers active, prefetch always valid)
    for (int s = 6; s < 2046; s += 6) {
        step(s,     0, false, false);
        step(s + 1, 1, false, false);
        step(s + 2, 2, false, false);
        step(s + 3, 0, false, false);
        step(s + 4, 1, false, false);
        step(s + 5, 2, false, false);
    }
    // epilogue (drain, masked; final-h at s = 2047/2049/2051 per layer)
    step(2046, 0, true, true);
    step(2047, 1, true, true);
    step(2048, 2, true, true);
    step(2049, 0, true, true);
    step(2050, 1, true, true);
    step(2051, 2, true, true);

    // ---- fused MLP head (hfin visible after the last step's barrier) ----
    if (tid < 4 * OO) {                   // 72 threads x 3 layers
        #pragma unroll
        for (int ml = 0; ml < NL; ++ml) {
            float a = b1[tid];
            #pragma unroll
            for (int k = 0; k < HH; ++k) a += hfin[ml][k] * W1[tid * HH + k];
            h1s[ml][tid] = 0.5f * a * (1.0f + erff(a * 0.70710678118654752f));
        }
    }
    __syncthreads();
    if (tid < NL * OO) {                  // 54 threads
        const int ol = tid / OO, o = tid % OO;
        float a = b2[o];
        #pragma unroll
        for (int m = 0; m < 4 * OO; ++m) a += h1s[ol][m] * W2[o * (4 * OO) + m];
        outp[((size_t)ol * BB + bg) * OO + o] = a;
    }
}

extern "C" void kernel_launch(void* const* d_in, const int* in_sizes, int n_in,
                              void* d_out, int out_size, void* d_ws, size_t ws_size,
                              hipStream_t stream) {
    const float* x    = (const float*)d_in[0];
    const float* Wih0 = (const float*)d_in[1];
    const float* Whh0 = (const float*)d_in[2];
    const float* bih0 = (const float*)d_in[3];
    const float* bhh0 = (const float*)d_in[4];
    const float* Wih1 = (const float*)d_in[5];
    const float* Whh1 = (const float*)d_in[6];
    const float* bih1 = (const float*)d_in[7];
    const float* bhh1 = (const float*)d_in[8];
    const float* Wih2 = (const float*)d_in[9];
    const float* Whh2 = (const float*)d_in[10];
    const float* bih2 = (const float*)d_in[11];
    const float* bhh2 = (const float*)d_in[12];
    const float* W1   = (const float*)d_in[13];
    const float* b1   = (const float*)d_in[14];
    const float* W2   = (const float*)d_in[15];
    const float* b2   = (const float*)d_in[16];

    float* out    = (float*)d_out;                 // [3,512,18] = 27648 floats
    float* hidden = out + NL * BB * OO;            // [3,512,33] = 50688 floats

    lstm_skew2_kernel<<<BB, 128, 0, stream>>>(
        x, Wih0, Whh0, bih0, bhh0, Wih1, Whh1, bih1, bhh1,
        Wih2, Whh2, bih2, bhh2, W1, b1, W2, b2, hidden, out);
}

// Round 11
// 1036.952 us; speedup vs baseline: 1.8762x; 1.0482x over previous
//
#include <hip/hip_runtime.h>
#include <math.h>

// Problem constants (from reference)
#define TT 2048
#define BB 512
#define II 11
#define HH 33
#define NL 3
#define OO 18
#define HSLOT 48          // halves per LDS vector slot (96 B, 16B-aligned slots)
#define XPAD 16           // halves per staged-x row (32 B, b128-aligned reads)

typedef _Float16 h2 __attribute__((ext_vector_type(2)));
typedef _Float16 h8 __attribute__((ext_vector_type(8)));   // 16 B -> ds_read_b128

// fast sigmoid / tanh via v_exp_f32 + v_rcp_f32 (saturate correctly at +-inf)
__device__ __forceinline__ float sigm_f(float x) {
    float e = __expf(-x);
    return __builtin_amdgcn_rcpf(1.0f + e);
}
__device__ __forceinline__ float tanh_f(float x) {
    float e = __expf(2.0f * x);
    return 1.0f - 2.0f * __builtin_amdgcn_rcpf(e + 1.0f);
}

// guarded fp32->fp16 row-slice loads (zero-pad past rem)
__device__ __forceinline__ h8 gldh8(const float* p, int k0, int rem) {
    h8 v;
    #pragma unroll
    for (int i = 0; i < 8; ++i) v[i] = (_Float16)((k0 + i < rem) ? p[k0 + i] : 0.0f);
    return v;
}
__device__ __forceinline__ h2 gldh2(const float* p, int k0, int rem) {
    h2 v;
    v.x = (_Float16)((k0 + 0 < rem) ? p[k0 + 0] : 0.0f);
    v.y = (_Float16)((k0 + 1 < rem) ? p[k0 + 1] : 0.0f);
    return v;
}

// v_dot2_f32_f16: 2 MACs/op, fp32 accumulate
#define FD(a, p, q) a = __builtin_amdgcn_fdot2((p), (q), a, false)
// one 2-half slice fed to all 8 chains (4 input-side + 4 own-h-side)
#define DUO(vi_, vo_, SEL) do { \
    FD(a0i, (vi_).SEL, (xw0).SEL); FD(a1i, (vi_).SEL, (xw1).SEL); \
    FD(a2i, (vi_).SEL, (xw2).SEL); FD(a3i, (vi_).SEL, (xw3).SEL); \
    FD(a0h, (vo_).SEL, (hw0).SEL); FD(a1h, (vo_).SEL, (hw1).SEL); \
    FD(a2h, (vo_).SEL, (hw2).SEL); FD(a3h, (vo_).SEL, (hw3).SEL); } while (0)
#define DUOQ(vi_, vo_, xq0, xq1, xq2, xq3, hq0, hq1, hq2, hq3) do { \
    const h8 xw0 = (xq0), xw1 = (xq1), xw2 = (xq2), xw3 = (xq3); \
    const h8 hw0 = (hq0), hw1 = (hq1), hw2 = (hq2), hw3 = (hq3); \
    DUO(vi_, vo_, s01); DUO(vi_, vo_, s23); \
    DUO(vi_, vo_, s45); DUO(vi_, vo_, s67); } while (0)

// CHAMPION (R6, 1041.6 us; three-run-stable 1042-1053). Layer-pipelined LSTM,
// ONE LANE PER UNIT, fused MLP head. grid = 512 blocks (one batch element),
// block = 128 threads (2 waves), 1 wave/SIMD.
// Session conclusion (11 rounds): per-step ~1230 cy = 136 fdot2 issue (~270+)
// + LDS read latency (~120) + trans tail (~150) + write/drain/barrier (~200)
// + misc. Falsified alternatives: occupancy 2w/SIMD (R1/R3: worse), pk_fma /
// scalar-fma engines (R2/R3: worse), chain restructure (R4: null), LDS weight
// laundering (R5: much worse), barrier elision via epoch+in-wave LDS (R7:
// worse), dual-batch in-wave (R8: worse), readlane/SGPR broadcast (R9:
// worse), skew-2 critical-path decoupling (R10: null). The step is issue +
// serial-fabric bound; gfx950 offers no cheaper wave-sync / all-lane
// broadcast primitive, and the 2048-step recurrence is mathematically serial.
// ~1042 us is the structural floor for this decomposition.
__global__ __launch_bounds__(128, 1) void lstm_pipeline_kernel(
    const float* __restrict__ x,
    const float* __restrict__ Wih0, const float* __restrict__ Whh0,
    const float* __restrict__ bih0, const float* __restrict__ bhh0,
    const float* __restrict__ Wih1, const float* __restrict__ Whh1,
    const float* __restrict__ bih1, const float* __restrict__ bhh1,
    const float* __restrict__ Wih2, const float* __restrict__ Whh2,
    const float* __restrict__ bih2, const float* __restrict__ bhh2,
    const float* __restrict__ W1, const float* __restrict__ b1,
    const float* __restrict__ W2, const float* __restrict__ b2,
    float* __restrict__ hidden_out,   // [3, 512, 33]
    float* __restrict__ outp)         // [3, 512, 18]
{
    __shared__ __align__(16) _Float16 xst[TT + 2][XPAD];   // staged x, 65.6 KB
    __shared__ __align__(16) _Float16 buf[2][NL + 1][HSLOT];
    __shared__ float hfin[NL][HH + 1];   // final h per layer (fp32, fused MLP)
    __shared__ float h1s[NL][4 * OO];    // MLP hidden

    const int tid = threadIdx.x;
    const int bg  = blockIdx.x;

    for (int i = tid; i < 2 * (NL + 1) * HSLOT; i += 128)
        ((_Float16*)buf)[i] = (_Float16)0.0f;

    // ---- x staging: pad cells zeroed; real cells filled (disjoint writes) ----
    for (int f = tid; f < (TT + 2) * XPAD; f += 128) {
        const int i = f & (XPAD - 1);
        const int t = f >> 4;
        if (i >= II || t >= TT) ((_Float16*)xst)[f] = (_Float16)0.0f;
    }
    {
        const float* xblk = x + (size_t)bg * TT * II;
        const float4* xf4 = (const float4*)xblk;          // 22528 floats = 5632 f4
        for (int f4 = tid; f4 < (TT * II) / 4; f4 += 128) {
            const float4 v = xf4[f4];
            const int e0 = 4 * f4;
            #pragma unroll
            for (int e = 0; e < 4; ++e) {
                const int idx = e0 + e;
                const int t = idx / II;                   // magic-mul
                const int i = idx - t * II;
                xst[t][i] = (_Float16)((&v.x)[e]);
            }
        }
    }

    const bool comp = (tid < 99);
    const int  u    = tid;
    const int  l    = (u < 33) ? 0 : (u < 66) ? 1 : 2;
    const int  j    = u - 33 * l;

    // ---- per-lane weights: 4 gates x (input 34 + own 34) halves, named regs ----
    h8 z8 = {0,0,0,0,0,0,0,0};
    h2 z2 = {(_Float16)0.0f, (_Float16)0.0f};
    h8 x00=z8,x01=z8,x02=z8,x03=z8; h2 x0t=z2;   // gate i, input side (W_ih row)
    h8 x10=z8,x11=z8,x12=z8,x13=z8; h2 x1t=z2;   // gate f
    h8 x20=z8,x21=z8,x22=z8,x23=z8; h2 x2t=z2;   // gate g
    h8 x30=z8,x31=z8,x32=z8,x33=z8; h2 x3t=z2;   // gate o
    h8 h00=z8,h01=z8,h02=z8,h03=z8; h2 h0t=z2;   // gate i, own-h side (W_hh row)
    h8 h10=z8,h11=z8,h12=z8,h13=z8; h2 h1t=z2;
    h8 h20=z8,h21=z8,h22=z8,h23=z8; h2 h2t=z2;
    h8 h30=z8,h31=z8,h32=z8,h33=z8; h2 h3t=z2;
    float b0 = 0.0f, b1v = 0.0f, b2v = 0.0f, b3v = 0.0f;

    if (comp) {
        const float* bip = (l == 0) ? bih0 : (l == 1) ? bih1 : bih2;
        const float* bhp = (l == 0) ? bhh0 : (l == 1) ? bhh1 : bhh2;
        b0  = bip[0 * HH + j] + bhp[0 * HH + j];
        b1v = bip[1 * HH + j] + bhp[1 * HH + j];
        b2v = bip[2 * HH + j] + bhp[2 * HH + j];
        b3v = bip[3 * HH + j] + bhp[3 * HH + j];

        const float* Wi = (l == 0) ? Wih0 : (l == 1) ? Wih1 : Wih2;
        const float* Wh = (l == 0) ? Whh0 : (l == 1) ? Whh1 : Whh2;
        const int kin = (l == 0) ? II : HH;
        const float* r0 = Wi + (0 * HH + j) * kin;
        const float* r1 = Wi + (1 * HH + j) * kin;
        const float* r2 = Wi + (2 * HH + j) * kin;
        const float* r3 = Wi + (3 * HH + j) * kin;
        x00=gldh8(r0,0,kin); x01=gldh8(r0,8,kin); x02=gldh8(r0,16,kin); x03=gldh8(r0,24,kin); x0t=gldh2(r0,32,kin);
        x10=gldh8(r1,0,kin); x11=gldh8(r1,8,kin); x12=gldh8(r1,16,kin); x13=gldh8(r1,24,kin); x1t=gldh2(r1,32,kin);
        x20=gldh8(r2,0,kin); x21=gldh8(r2,8,kin); x22=gldh8(r2,16,kin); x23=gldh8(r2,24,kin); x2t=gldh2(r2,32,kin);
        x30=gldh8(r3,0,kin); x31=gldh8(r3,8,kin); x32=gldh8(r3,16,kin); x33=gldh8(r3,24,kin); x3t=gldh2(r3,32,kin);
        const float* s0 = Wh + (0 * HH + j) * HH;
        const float* s1 = Wh + (1 * HH + j) * HH;
        const float* s2 = Wh + (2 * HH + j) * HH;
        const float* s3 = Wh + (3 * HH + j) * HH;
        h00=gldh8(s0,0,HH); h01=gldh8(s0,8,HH); h02=gldh8(s0,16,HH); h03=gldh8(s0,24,HH); h0t=gldh2(s0,32,HH);
        h10=gldh8(s1,0,HH); h11=gldh8(s1,8,HH); h12=gldh8(s1,16,HH); h13=gldh8(s1,24,HH); h1t=gldh2(s1,32,HH);
        h20=gldh8(s2,0,HH); h21=gldh8(s2,8,HH); h22=gldh8(s2,16,HH); h23=gldh8(s2,24,HH); h2t=gldh2(s2,32,HH);
        h30=gldh8(s3,0,HH); h31=gldh8(s3,8,HH); h32=gldh8(s3,16,HH); h33=gldh8(s3,24,HH); h3t=gldh2(s3,32,HH);
    }

    __syncthreads();

    float c = 0.0f;

    // hoisted ping-pong pointers (compile-time selected in peeled steps)
    const _Float16* rin[2]  = { &buf[0][l][0],     &buf[1][l][0] };      // h input (l>0)
    const _Float16* rown[2] = { &buf[0][l + 1][0], &buf[1][l + 1][0] };  // own-h vec
    _Float16*       wrp[2]  = { &buf[0][l + 1][j], &buf[1][l + 1][j] };
    const _Float16* xst0    = &xst[0][0];

    // one superstep; rp/check/out are compile-time constants at call sites
    auto step = [&](int s, int rp, bool check, bool out)
        __attribute__((always_inline)) {
        const int wp = rp ^ 1;
        const bool active = check ? (comp && (s >= l) && (s - l < TT)) : comp;
        if (active) {
            // layer-0 reads its timestep row straight from staged x (overhang
            // halves land in later rows / pad -- finite values times zero
            // weights); layers 1,2 read the h ping-pong.
            const _Float16* ri = (l == 0) ? (xst0 + (s << 4)) : rin[rp];
            const h8* VI = (const h8*)ri;
            const h8 vi0 = VI[0], vi1 = VI[1], vi2 = VI[2], vi3 = VI[3];
            const h2 vit = *(const h2*)(ri + 32);
            const h8* VO = (const h8*)rown[rp];
            const h8 vo0 = VO[0], vo1 = VO[1], vo2 = VO[2], vo3 = VO[3];
            const h2 vot = *(const h2*)(rown[rp] + 32);

            // ---- single MAC phase: 8 independent 17-deep fdot2 chains ----
            float a0i = b0, a1i = b1v, a2i = b2v, a3i = b3v;
            float a0h = 0.0f, a1h = 0.0f, a2h = 0.0f, a3h = 0.0f;
            DUOQ(vi0, vo0, x00, x10, x20, x30, h00, h10, h20, h30);
            DUOQ(vi1, vo1, x01, x11, x21, x31, h01, h11, h21, h31);
            DUOQ(vi2, vo2, x02, x12, x22, x32, h02, h12, h22, h32);
            DUOQ(vi3, vo3, x03, x13, x23, x33, h03, h13, h23, h33);
            FD(a0i, vit, x0t); FD(a1i, vit, x1t);
            FD(a2i, vit, x2t); FD(a3i, vit, x3t);
            FD(a0h, vot, h0t); FD(a1h, vot, h1t);
            FD(a2h, vot, h2t); FD(a3h, vot, h3t);

            const float s0 = a0i + a0h;   // gate i
            const float s1 = a1i + a1h;   // gate f
            const float s2 = a2i + a2h;   // gate g
            const float s3 = a3i + a3h;   // gate o

            // ---- tail: 4 independent trans chains, then the c/h chain ----
            const float ig = sigm_f(s0);
            const float fg = sigm_f(s1);
            const float gg = tanh_f(s2);
            const float og = sigm_f(s3);
            c = __builtin_fmaf(fg, c, ig * gg);
            const float hnew = og * tanh_f(c);

            *wrp[wp] = (_Float16)hnew;
            if (out && (s - l == TT - 1)) {
                hidden_out[((size_t)l * BB + bg) * HH + j] = hnew;
                hfin[l][j] = hnew;
            }
        }
        __syncthreads();
    };

    // prologue (pipeline fill, masked)
    step(0, 0, true, false);
    step(1, 1, true, false);
    // steady state: s = 2..2043 as constant-rp pairs (no checks, no outputs)
    for (int s = 2; s < TT - 4; s += 2) {
        step(s,     0, false, false);
        step(s + 1, 1, false, false);
    }
    // tail of steady state + epilogue (drain + final-h outputs)
    step(TT - 4, 0, false, false);   // s=2044
    step(TT - 3, 1, false, false);   // s=2045
    step(TT - 2, 0, false, false);   // s=2046
    step(TT - 1, 1, false, true);    // s=2047: l0 writes hT
    step(TT,     0, true,  true);    // s=2048: l1 writes hT
    step(TT + 1, 1, true,  true);    // s=2049: l2 writes hT

    // ---- fused MLP head (hfin visible after the last step's barrier) ----
    // h1 = gelu_exact(hfin @ W1^T + b1) [3,72]; out = h1 @ W2^T + b2 [3,18]
    if (tid < 4 * OO) {                   // 72 threads x 3 layers
        #pragma unroll
        for (int ml = 0; ml < NL; ++ml) {
            float a = b1[tid];
            #pragma unroll
            for (int k = 0; k < HH; ++k) a += hfin[ml][k] * W1[tid * HH + k];
            h1s[ml][tid] = 0.5f * a * (1.0f + erff(a * 0.70710678118654752f));
        }
    }
    __syncthreads();
    if (tid < NL * OO) {                  // 54 threads
        const int ol = tid / OO, o = tid % OO;
        float a = b2[o];
        #pragma unroll
        for (int m = 0; m < 4 * OO; ++m) a += h1s[ol][m] * W2[o * (4 * OO) + m];
        outp[((size_t)ol * BB + bg) * OO + o] = a;
    }
}

extern "C" void kernel_launch(void* const* d_in, const int* in_sizes, int n_in,
                              void* d_out, int out_size, void* d_ws, size_t ws_size,
                              hipStream_t stream) {
    const float* x    = (const float*)d_in[0];
    const float* Wih0 = (const float*)d_in[1];
    const float* Whh0 = (const float*)d_in[2];
    const float* bih0 = (const float*)d_in[3];
    const float* bhh0 = (const float*)d_in[4];
    const float* Wih1 = (const float*)d_in[5];
    const float* Whh1 = (const float*)d_in[6];
    const float* bih1 = (const float*)d_in[7];
    const float* bhh1 = (const float*)d_in[8];
    const float* Wih2 = (const float*)d_in[9];
    const float* Whh2 = (const float*)d_in[10];
    const float* bih2 = (const float*)d_in[11];
    const float* bhh2 = (const float*)d_in[12];
    const float* W1   = (const float*)d_in[13];
    const float* b1   = (const float*)d_in[14];
    const float* W2   = (const float*)d_in[15];
    const float* b2   = (const float*)d_in[16];

    float* out    = (float*)d_out;                 // [3,512,18] = 27648 floats
    float* hidden = out + NL * BB * OO;            // [3,512,33] = 50688 floats

    lstm_pipeline_kernel<<<BB, 128, 0, stream>>>(
        x, Wih0, Whh0, bih0, bhh0, Wih1, Whh1, bih1, bhh1,
        Wih2, Whh2, bih2, bhh2, W1, b1, W2, b2, hidden, out);
}